// Round 4
// baseline (44.942 us; speedup 1.0000x reference)
//
#include <hip/hip_runtime.h>

#define HID 128
#define FEAT 16
#define N_PER 100000
#define NUM_ACTIONS 75000
#define N_NODES 100000
#define N_GRAPHS 512

// ws float layout:
// [0..143]   wg   = glob_W @ p   (globs part 0..127, feat part 128..143)
// [144..287] wn   = node_W @ p   (nodes part 144..271, feat part 272..287)
// [288..415] qe   = (e2_W @ p)[0:128]
// [416..687] w1   = e1_W @ qEE   (row 416..543, feat 544..559, col 560..687)
// [688] cg=glob_b.p  [689] cn=node_b.p  [690] ce=e1_b.qEE+e2_b.p  [691] pb
// [1024 ..]             nscal: float4 per node (x=.wr, y=.wc, z=.wn)
// [1024+4*N_NODES ..]   gscal: float per graph
#define NSCAL_OFF 1024
#define GSCAL_OFF (NSCAL_OFF + 4 * N_NODES)

__device__ __forceinline__ float dot4(float4 a, float4 b) {
    return a.x * b.x + a.y * b.y + a.z * b.z + a.w * b.w;
}

// 32 blocks x 16 waves.
// Phase 0 (per block, redundant): qEE[128] and wg[128] into LDS.
// Phase 1: grid-stride 1204 wave-dots: 692 folded weights + 512 gscal.
__global__ __launch_bounds__(1024) void fold_kernel(
    const float* __restrict__ glob_W, const float* __restrict__ glob_b,
    const float* __restrict__ node_W, const float* __restrict__ node_b,
    const float* __restrict__ e1_W,  const float* __restrict__ e1_b,
    const float* __restrict__ e2_W,  const float* __restrict__ e2_b,
    const float* __restrict__ pol_W, const float* __restrict__ pol_b,
    const float* __restrict__ globs, float* __restrict__ ws)
{
    __shared__ float qEE[HID];
    __shared__ float wgs[HID];
    const int t = threadIdx.x, wave = t >> 6, lane = t & 63;
    const float2 p2 = *(const float2*)&pol_W[2 * lane];

    for (int k = wave; k < 256; k += 16) {
        const float* rp = (k < HID) ? &e2_W[(HID + k) * HID] : &glob_W[(k - HID) * HID];
        const float2 x = *(const float2*)&rp[2 * lane];
        float acc = x.x * p2.x + x.y * p2.y;
        #pragma unroll
        for (int m = 32; m; m >>= 1) acc += __shfl_xor(acc, m);
        if (lane == 0) { if (k < HID) qEE[k] = acc; else wgs[k - HID] = acc; }
    }
    __syncthreads();
    const float2 q2 = *(const float2*)&qEE[2 * lane];
    const float2 g2 = *(const float2*)&wgs[2 * lane];

    const int gw = blockIdx.x * 16 + wave;
    for (int d = gw; d < 692 + N_GRAPHS; d += 512) {
        float acc;
        if (d < 144) {
            const float2 x = *(const float2*)&glob_W[d * HID + 2 * lane];
            acc = x.x * p2.x + x.y * p2.y;
        } else if (d < 288) {
            const float2 x = *(const float2*)&node_W[(d - 144) * HID + 2 * lane];
            acc = x.x * p2.x + x.y * p2.y;
        } else if (d < 416) {
            const float2 x = *(const float2*)&e2_W[(d - 288) * HID + 2 * lane];
            acc = x.x * p2.x + x.y * p2.y;
        } else if (d < 688) {
            const float2 x = *(const float2*)&e1_W[(d - 416) * HID + 2 * lane];
            acc = x.x * q2.x + x.y * q2.y;
        } else if (d == 688) {
            const float2 x = *(const float2*)&glob_b[2 * lane];
            acc = x.x * p2.x + x.y * p2.y;
        } else if (d == 689) {
            const float2 x = *(const float2*)&node_b[2 * lane];
            acc = x.x * p2.x + x.y * p2.y;
        } else if (d == 690) {
            const float2 x1 = *(const float2*)&e1_b[2 * lane];
            const float2 x2 = *(const float2*)&e2_b[2 * lane];
            acc = x1.x * q2.x + x1.y * q2.y + x2.x * p2.x + x2.y * p2.y;
        } else if (d == 691) {
            if (lane == 0) ws[691] = pol_b[0];
            continue;
        } else {
            const float2 x = *(const float2*)&globs[(d - 692) * HID + 2 * lane];
            acc = x.x * g2.x + x.y * g2.y;
        }
        #pragma unroll
        for (int m = 32; m; m >>= 1) acc += __shfl_xor(acc, m);
        if (lane == 0) {
            if (d < 692) ws[d] = acc;
            else         ws[GSCAL_OFF + (d - 692)] = acc;
        }
    }
}

// Pure nodes stream: quarter-wave (16 lanes) per row, two contiguous float4
// loads per lane (cols [4q..4q+3] and [64+4q..64+4q+3]), 4 rows in flight
// per wave, grid-stride over 2048 blocks.
__global__ __launch_bounds__(256) void precompute_kernel(
    const float* __restrict__ nodes, float* __restrict__ ws)
{
    const int t = threadIdx.x, q = t & 15, quarter = t >> 4;  // 16 quarters/block
    const int c1 = 4 * q, c2 = 64 + 4 * q;

    const float4 wr1 = *(const float4*)&ws[416 + c1];
    const float4 wr2 = *(const float4*)&ws[416 + c2];
    const float4 wc1 = *(const float4*)&ws[560 + c1];
    const float4 wc2 = *(const float4*)&ws[560 + c2];
    const float4 wn1 = *(const float4*)&ws[144 + c1];
    const float4 wn2 = *(const float4*)&ws[144 + c2];

    for (int h = blockIdx.x * 16 + quarter; h < N_NODES; h += gridDim.x * 16) {
        const float4 x1 = *(const float4*)&nodes[h * HID + c1];
        const float4 x2 = *(const float4*)&nodes[h * HID + c2];
        float ar = dot4(x1, wr1) + dot4(x2, wr2);
        float ac = dot4(x1, wc1) + dot4(x2, wc2);
        float an_ = dot4(x1, wn1) + dot4(x2, wn2);
        #pragma unroll
        for (int m = 8; m; m >>= 1) {
            ar  += __shfl_xor(ar, m);
            ac  += __shfl_xor(ac, m);
            an_ += __shfl_xor(an_, m);
        }
        if (q == 0) *(float4*)&ws[NSCAL_OFF + 4 * h] = make_float4(ar, ac, an_, 0.f);
    }
}

// Each block: wave0 = glob (4 actions, 16 lanes each), wave1 = node,
// wave2+3 = edge (2 actions/wave, 32 lanes per action).
__global__ __launch_bounds__(256) void actions_kernel(
    const float* __restrict__ edges,
    const float* __restrict__ ag, const float* __restrict__ an,
    const float* __restrict__ ae,
    const int* __restrict__ row, const int* __restrict__ col,
    const int* __restrict__ U, const int* __restrict__ V,
    const int* __restrict__ E,
    const float* __restrict__ ws, float* __restrict__ out)
{
    const int b    = blockIdx.x;            // 0..6249
    const int wave = threadIdx.x >> 6;
    const int lane = threadIdx.x & 63;

    if (wave < 2) {
        const bool isg = (wave == 0);
        const int qtr = lane >> 4, ql = lane & 15;
        const int al  = 4 * b + qtr;          // branch-local action
        const int gl  = 4 * al;               // branch-local row base
        const float* feats = isg ? ag : an;
        const int* idx     = isg ? U : V;
        const int wbase    = isg ? 0 : 144;

        float p = 0.f;
        if ((ql & 3) == 0) {
            const int id = idx[gl + (ql >> 2)];
            p = isg ? ws[GSCAL_OFF + id] : ws[NSCAL_OFF + 4 * id + 2];
        }
        const float4 f  = *(const float4*)&feats[gl * FEAT + 4 * ql];
        const float4 wf = *(const float4*)&ws[wbase + HID + 4 * (ql & 3)];
        p += dot4(f, wf);
        #pragma unroll
        for (int m = 8; m; m >>= 1) p += __shfl_xor(p, m);
        if (ql == 0)
            out[(isg ? 0 : 25000) + al] = p + 4.f * ws[isg ? 688 : 689] + ws[691];
    } else {
        const int j = b + 6250 * (wave - 2);  // 0..12499
        const int s = lane & 31;
        const int al = 2 * j + (lane >> 5);   // branch-local action 0..24999
        const int gl = 4 * al;                // branch-local row base

        // dependent gather chain first: E -> row/col -> nscal
        const int4 e4 = *(const int4*)&E[gl];
        int e[4] = { e4.x, e4.y, e4.z, e4.w };
        float p = 0.f;
        if (s < 8) {
            const int ei = e[s & 3];
            const int id = (s < 4) ? row[ei] : col[ei];
            p = ws[NSCAL_OFF + 4 * id + ((s < 4) ? 0 : 1)];
        }

        const float4 we = *(const float4*)&ws[288 + 4 * s];
        #pragma unroll
        for (int i = 0; i < 4; ++i) {
            const float4 x = *(const float4*)&edges[e[i] * HID + 4 * s];
            p += dot4(x, we);
        }
        if (s < 16) {
            const float4 f  = *(const float4*)&ae[gl * FEAT + 4 * s];
            const float4 wf = *(const float4*)&ws[544 + 4 * (s & 3)];
            p += dot4(f, wf);
        }
        #pragma unroll
        for (int m = 16; m; m >>= 1) p += __shfl_xor(p, m);
        if (s == 0) out[50000 + al] = p + 4.f * ws[690] + ws[691];
    }
}

extern "C" void kernel_launch(void* const* d_in, const int* in_sizes, int n_in,
                              void* d_out, int out_size, void* d_ws, size_t ws_size,
                              hipStream_t stream)
{
    const float* globs  = (const float*)d_in[0];
    const float* nodes  = (const float*)d_in[1];
    const float* edges  = (const float*)d_in[2];
    const float* ag     = (const float*)d_in[3];
    const float* an     = (const float*)d_in[4];
    const float* ae     = (const float*)d_in[5];
    const float* glob_W = (const float*)d_in[6];
    const float* glob_b = (const float*)d_in[7];
    const float* node_W = (const float*)d_in[8];
    const float* node_b = (const float*)d_in[9];
    const float* e1_W   = (const float*)d_in[10];
    const float* e1_b   = (const float*)d_in[11];
    const float* e2_W   = (const float*)d_in[12];
    const float* e2_b   = (const float*)d_in[13];
    const float* pol_W  = (const float*)d_in[14];
    const float* pol_b  = (const float*)d_in[15];
    const int*   row    = (const int*)d_in[16];
    const int*   col    = (const int*)d_in[17];
    const int*   U      = (const int*)d_in[18];
    const int*   V      = (const int*)d_in[20];
    const int*   E      = (const int*)d_in[22];

    float* ws  = (float*)d_ws;
    float* out = (float*)d_out;

    hipLaunchKernelGGL(fold_kernel, dim3(32), dim3(1024), 0, stream,
                       glob_W, glob_b, node_W, node_b, e1_W, e1_b, e2_W, e2_b,
                       pol_W, pol_b, globs, ws);
    hipLaunchKernelGGL(precompute_kernel, dim3(2048), dim3(256), 0, stream,
                       nodes, ws);
    hipLaunchKernelGGL(actions_kernel, dim3(6250), dim3(256), 0, stream,
                       edges, ag, an, ae, row, col, U, V, E, ws, out);
}